// Round 2
// baseline (1601.102 us; speedup 1.0000x reference)
//
#include <hip/hip_runtime.h>

// HeaNet: SchNet-like GNN on MI355X.
// R2: kill register spills. Block = 4 waves x 64 edges; each wave owns a
// 32-feature quarter (fq) -> 32 accumulators/thread instead of 128.
// t[64][128] goes through LDS (stride 129: conflict-free both phases).
// W1/W2/bias reads are wave-uniform (fq via readfirstlane) -> s_load broadcast.

#define NNODES 8192
#define NGRAPH 32
#define NPER   256
#define NELEM  5
#define NEDGE  131072
#define HD     128
#define FD     128
#define GD     50
#define LL     6
#define NC     160
#define CUT    10.0f
#define LOG2_  0.69314718055994531f

__device__ __forceinline__ float ssp(float x) {
    // softplus(x) - log(2), numerically stable
    float m = fmaxf(x, 0.0f);
    float z = __expf(-fabsf(x));
    return m + __logf(1.0f + z) - LOG2_;
}

// ---------- setup kernels (layer-invariant) ----------

__global__ void hist_edges(const int* __restrict__ ei, const int* __restrict__ comp_id,
                           int* __restrict__ hist) {
    __shared__ int lh[NC];
    int tid = threadIdx.x;
    if (tid < NC) lh[tid] = 0;
    __syncthreads();
    int e = blockIdx.x * 256 + tid;
    int dst = ei[NEDGE + e];
    atomicAdd(&lh[comp_id[dst]], 1);
    __syncthreads();
    if (tid < NC) atomicAdd(&hist[tid], lh[tid]);
}

__global__ void count_nodes(const int* __restrict__ comp_id, int* __restrict__ counts) {
    int n = blockIdx.x * 256 + threadIdx.x;
    atomicAdd(&counts[comp_id[n]], 1);
}

__global__ void scan_offsets(const int* __restrict__ hist, const int* __restrict__ counts,
                             int* __restrict__ cursor, float* __restrict__ countsf) {
    if (threadIdx.x == 0) {
        int run = 0;
        for (int c = 0; c < NC; ++c) { cursor[c] = run; run += hist[c]; }
    }
    if (threadIdx.x < NC) countsf[threadIdx.x] = (float)counts[threadIdx.x];
}

__global__ void scatter_edges(const float* __restrict__ pos, const int* __restrict__ ei,
                              const int* __restrict__ comp_id, int* __restrict__ cursor,
                              float* __restrict__ ew_s, float* __restrict__ c_s,
                              int* __restrict__ src_s, int* __restrict__ cid_s) {
    int e = blockIdx.x * 256 + threadIdx.x;
    int s = ei[e], d = ei[NEDGE + e];
    float dx = pos[3*s]   - pos[3*d];
    float dy = pos[3*s+1] - pos[3*d+1];
    float dz = pos[3*s+2] - pos[3*d+2];
    float d2 = dx*dx + dy*dy + dz*dz;
    float ew = sqrtf(d2);
    float C  = CUT / (1e-10f + d2) - 1.0f;
    int cid = comp_id[d];
    int idx = atomicAdd(&cursor[cid], 1);
    ew_s[idx] = ew; c_s[idx] = C; src_s[idx] = s; cid_s[idx] = cid;
}

// xh_all[l][n][f] = (emb[z[n]] @ cf_lin1_w[l])[f]
// block = 4 waves x 64 nodes; wave fq owns features [fq*32, fq*32+32)
__global__ __launch_bounds__(256) void xh_kernel(const float* __restrict__ emb,
                                                 const int* __restrict__ z,
                                                 const float* __restrict__ cf1,
                                                 float* __restrict__ xh_all) {
    const int lane = threadIdx.x & 63;
    const int fq = __builtin_amdgcn_readfirstlane(threadIdx.x >> 6);
    const int l = blockIdx.y;
    const int n = blockIdx.x * 64 + lane;
    const float* h = emb + z[n] * HD;
    const float* w = cf1 + l * HD * FD + fq * 32;
    float acc[32];
    #pragma unroll
    for (int j = 0; j < 32; ++j) acc[j] = 0.0f;
    #pragma unroll 1
    for (int k = 0; k < HD; k += 4) {
        float4 hk = *(const float4*)(h + k);
        const float* w0 = w + k * FD;
        #pragma unroll
        for (int j = 0; j < 32; ++j) {
            float a = acc[j];
            a = fmaf(hk.x, w0[j], a);
            a = fmaf(hk.y, w0[FD + j], a);
            a = fmaf(hk.z, w0[2 * FD + j], a);
            a = fmaf(hk.w, w0[3 * FD + j], a);
            acc[j] = a;
        }
    }
    float* o = xh_all + ((long)l * NNODES + n) * FD + fq * 32;
    #pragma unroll
    for (int j = 0; j < 32; j += 4)
        *(float4*)(o + j) = make_float4(acc[j], acc[j+1], acc[j+2], acc[j+3]);
}

__global__ void types_init(const float* __restrict__ emb, const int* __restrict__ comps_z,
                           float* __restrict__ types) {
    int c = blockIdx.x; int f = threadIdx.x;
    types[c * HD + f] = emb[comps_z[c] * HD + f];
}

// ---------- hot kernel: per-edge filter MLP + message + comp aggregation ----------
// Block = 256 threads = 4 waves over (64 edges) x (4 feature quarters).
// grid = (E/64, L). t[64][128] via LDS stride 129 (conflict-free).
__global__ __launch_bounds__(256) void edge_kernel(
    const float* __restrict__ ew_s, const float* __restrict__ c_s,
    const int* __restrict__ src_s, const int* __restrict__ cid_s,
    const float* __restrict__ w1_, const float* __restrict__ b1_,
    const float* __restrict__ w2_, const float* __restrict__ b2_,
    const float* __restrict__ xh_all, float* __restrict__ comp_acc)
{
    __shared__ float t_lds[64 * 129];
    const int lane = threadIdx.x & 63;
    const int fq = __builtin_amdgcn_readfirstlane(threadIdx.x >> 6);
    const int l = blockIdx.y;
    const int e = blockIdx.x * 64 + lane;

    const float ew = ew_s[e];
    const float Ce = c_s[e];
    const int src  = src_s[e];
    const int cid  = cid_s[e];

    const float* w1 = w1_ + l * GD * FD + fq * 32;    // [g][f-quarter]
    const float* b1 = b1_ + l * FD + fq * 32;
    const float* w2 = w2_ + l * FD * FD + fq * 32;    // [fi][fo-quarter] (original layout)
    const float* b2 = b2_ + l * FD + fq * 32;

    // ---- stage 1: t = ssp(edge_attr @ W1 + b1), this wave's 32 features ----
    float acc[32];
    #pragma unroll
    for (int j = 0; j < 32; ++j) acc[j] = b1[j];
    const float delta = CUT / (GD - 1);
    const float coeff = -0.5f / (delta * delta);
    #pragma unroll 2
    for (int g = 0; g < GD; ++g) {
        float dd = ew - g * delta;
        float a = __expf(coeff * dd * dd);
        const float* w1g = w1 + g * FD;
        #pragma unroll
        for (int j = 0; j < 32; ++j) acc[j] = fmaf(a, w1g[j], acc[j]);
    }
    float* trow = &t_lds[lane * 129 + fq * 32];
    #pragma unroll
    for (int j = 0; j < 32; ++j) trow[j] = ssp(acc[j]);
    __syncthreads();

    // ---- stage 2: W[e][fo] = t[e][:] @ W2[:, fo] + b2, fo in this quarter ----
    float acc2[32];
    #pragma unroll
    for (int j = 0; j < 32; ++j) acc2[j] = b2[j];
    const float* tread = &t_lds[lane * 129];
    #pragma unroll 2
    for (int fi = 0; fi < FD; ++fi) {
        float tv = tread[fi];
        const float* w2r = w2 + fi * FD;
        #pragma unroll
        for (int j = 0; j < 32; ++j) acc2[j] = fmaf(tv, w2r[j], acc2[j]);
    }

    // ---- stage 3: msg = xh[src] * W * C; reduce into comp_acc ----
    const float* xh = xh_all + ((long)l * NNODES + src) * FD + fq * 32;
    float msg[32];
    #pragma unroll
    for (int j = 0; j < 32; j += 4) {
        float4 xv = *(const float4*)(xh + j);
        msg[j]     = xv.x * acc2[j]     * Ce;
        msg[j + 1] = xv.y * acc2[j + 1] * Ce;
        msg[j + 2] = xv.z * acc2[j + 2] * Ce;
        msg[j + 3] = xv.w * acc2[j + 3] * Ce;
    }

    int c0 = __shfl(cid, 0);
    bool uni = (__all(cid == c0) != 0);
    float* cacc = comp_acc + (l * NC + cid) * FD + fq * 32;
    if (uni) {
        #pragma unroll
        for (int j = 0; j < 32; ++j) {
            float m = msg[j];
            #pragma unroll
            for (int s = 32; s > 0; s >>= 1) m += __shfl_xor(m, s);
            if (lane == j) atomicAdd(&cacc[j], m);   // spread atomics over lanes 0..31
        }
    } else {
        #pragma unroll
        for (int j = 0; j < 32; ++j) atomicAdd(&cacc[j], msg[j]);
    }
}

// ---------- per-component update: x = ssp(comp@cf2+b)@intw+b; types += x ----------
__global__ __launch_bounds__(128) void comp_kernel(
    const float* __restrict__ comp_acc, const float* __restrict__ countsf,
    const float* __restrict__ cf2w, const float* __restrict__ cf2b,
    const float* __restrict__ intw, const float* __restrict__ intb,
    float* __restrict__ types)
{
    int c = blockIdx.x, l = blockIdx.y, f = threadIdx.x;
    __shared__ float comp[FD];
    __shared__ float sx[FD];
    comp[f] = comp_acc[(l * NC + c) * FD + f] / countsf[c];
    __syncthreads();
    float acc = cf2b[l * HD + f];
    const float* w = cf2w + l * FD * HD;
    #pragma unroll 1
    for (int k = 0; k < FD; ++k) acc = fmaf(comp[k], w[k * HD + f], acc);
    sx[f] = ssp(acc);
    __syncthreads();
    float acc2 = intb[l * HD + f];
    const float* wi = intw + l * HD * HD;
    #pragma unroll 1
    for (int k = 0; k < HD; ++k) acc2 = fmaf(sx[k], wi[k * HD + f], acc2);
    atomicAdd(&types[c * HD + f], acc2);
}

// ---------- readout: out[b] = sum_c per_comp(c) ----------
__global__ __launch_bounds__(64) void readout_kernel(
    const float* __restrict__ types, const float* __restrict__ w1,
    const float* __restrict__ b1, const float* __restrict__ w2,
    const float* __restrict__ b2, float* __restrict__ out)
{
    int b = blockIdx.x, lane = threadIdx.x;
    float sum = 0.0f;
    for (int cc = 0; cc < NELEM; ++cc) {
        int c = b * NELEM + cc;
        float acc = b1[lane];
        const float* tr = types + c * HD;
        #pragma unroll 1
        for (int k = 0; k < HD; ++k) acc = fmaf(tr[k], w1[k * 64 + lane], acc);
        sum += ssp(acc) * w2[lane];
    }
    #pragma unroll
    for (int s = 32; s > 0; s >>= 1) sum += __shfl_xor(sum, s);
    if (lane == 0) out[b] = sum + (float)NELEM * b2[0];
}

extern "C" void kernel_launch(void* const* d_in, const int* in_sizes, int n_in,
                              void* d_out, int out_size, void* d_ws, size_t ws_size,
                              hipStream_t stream) {
    (void)in_sizes; (void)n_in; (void)out_size; (void)ws_size;
    const float* pos     = (const float*)d_in[0];
    const float* emb     = (const float*)d_in[1];
    const float* mlp_w1  = (const float*)d_in[2];
    const float* mlp_b1  = (const float*)d_in[3];
    const float* mlp_w2  = (const float*)d_in[4];
    const float* mlp_b2  = (const float*)d_in[5];
    const float* cf1     = (const float*)d_in[6];
    const float* cf2w    = (const float*)d_in[7];
    const float* cf2b    = (const float*)d_in[8];
    const float* intw    = (const float*)d_in[9];
    const float* intb    = (const float*)d_in[10];
    const float* ow1     = (const float*)d_in[11];
    const float* ob1     = (const float*)d_in[12];
    const float* ow2     = (const float*)d_in[13];
    const float* ob2     = (const float*)d_in[14];
    const int*   z       = (const int*)d_in[15];
    const int*   comp_id = (const int*)d_in[16];
    const int*   ei      = (const int*)d_in[17];
    const int*   comps_z = (const int*)d_in[18];
    float* out = (float*)d_out;

    char* ws = (char*)d_ws;
    size_t off = 0;
    auto alloc = [&](size_t bytes) -> void* {
        void* p = ws + off;
        off += (bytes + 255) & ~(size_t)255;
        return p;
    };
    // zeroed prefix: comp_acc | hist | counts
    float* comp_acc = (float*)alloc((size_t)LL * NC * FD * 4);
    int*   hist     = (int*)  alloc(NC * 4);
    int*   counts   = (int*)  alloc(NC * 4);
    size_t zero_bytes = off;
    int*   cursor   = (int*)  alloc(NC * 4);
    float* countsf  = (float*)alloc(NC * 4);
    float* ew_s     = (float*)alloc((size_t)NEDGE * 4);
    float* c_s      = (float*)alloc((size_t)NEDGE * 4);
    int*   src_s    = (int*)  alloc((size_t)NEDGE * 4);
    int*   cid_s    = (int*)  alloc((size_t)NEDGE * 4);
    float* xh_all   = (float*)alloc((size_t)LL * NNODES * FD * 4);
    float* types    = (float*)alloc((size_t)NC * HD * 4);

    hipMemsetAsync(d_ws, 0, zero_bytes, stream);

    hist_edges   <<<NEDGE / 256, 256, 0, stream>>>(ei, comp_id, hist);
    count_nodes  <<<NNODES / 256, 256, 0, stream>>>(comp_id, counts);
    scan_offsets <<<1, 256, 0, stream>>>(hist, counts, cursor, countsf);
    scatter_edges<<<NEDGE / 256, 256, 0, stream>>>(pos, ei, comp_id, cursor,
                                                   ew_s, c_s, src_s, cid_s);
    xh_kernel    <<<dim3(NNODES / 64, LL), 256, 0, stream>>>(emb, z, cf1, xh_all);
    types_init   <<<NC, HD, 0, stream>>>(emb, comps_z, types);
    edge_kernel  <<<dim3(NEDGE / 64, LL), 256, 0, stream>>>(ew_s, c_s, src_s, cid_s,
                                                            mlp_w1, mlp_b1, mlp_w2, mlp_b2,
                                                            xh_all, comp_acc);
    comp_kernel  <<<dim3(NC, LL), 128, 0, stream>>>(comp_acc, countsf, cf2w, cf2b,
                                                    intw, intb, types);
    readout_kernel<<<NGRAPH, 64, 0, stream>>>(types, ow1, ob1, ow2, ob2, out);
}

// Round 4
// 785.166 us; speedup vs baseline: 2.0392x; 2.0392x over previous
//
#include <hip/hip_runtime.h>

// HeaNet: SchNet-like GNN on MI355X.
// R4 = R3's cid-padding (every 64-edge group cid-uniform -> only the
// butterfly+1-atomic path survives; dummy slots Ce=0 are mathematically inert)
// with the LDS stride reverted to 129. R3's stride=127 overlapped adjacent
// 128-float rows by one word (row r elem 127 == row r+1 elem 0) -> race.
// 129: bank = (lane+c)%32 -> 2 lanes/bank = free (measured 0 conflicts in R2).

#define NNODES 8192
#define NGRAPH 32
#define NPER   256
#define NELEM  5
#define NEDGE  131072
#define HD     128
#define FD     128
#define GD     50
#define LL     6
#define NC     160
#define CUT    10.0f
#define LOG2_  0.69314718055994531f

// padded edge capacity: sum of per-cid align64 ranges <= E + NC*63 = 141152;
// round to 552*256 = 141312 so fill kernel has no remainder.
#define PADE   141312
#define PADG   (PADE / 64)     // 2208 edge-groups
#define TSTR   129             // LDS leading stride (floats): conflict-free, no row overlap

__device__ __forceinline__ float ssp(float x) {
    // softplus(x) - log(2), numerically stable
    float m = fmaxf(x, 0.0f);
    float z = __expf(-fabsf(x));
    return m + __logf(1.0f + z) - LOG2_;
}

// ---------- setup kernels (layer-invariant) ----------

__global__ void hist_edges(const int* __restrict__ ei, const int* __restrict__ comp_id,
                           int* __restrict__ hist) {
    __shared__ int lh[NC];
    int tid = threadIdx.x;
    if (tid < NC) lh[tid] = 0;
    __syncthreads();
    int e = blockIdx.x * 256 + tid;
    int dst = ei[NEDGE + e];
    atomicAdd(&lh[comp_id[dst]], 1);
    __syncthreads();
    if (tid < NC) atomicAdd(&hist[tid], lh[tid]);
}

__global__ void count_nodes(const int* __restrict__ comp_id, int* __restrict__ counts) {
    int n = blockIdx.x * 256 + threadIdx.x;
    atomicAdd(&counts[comp_id[n]], 1);
}

// aligned_start[c] = 64-aligned exclusive prefix of hist; cursor starts there.
__global__ void scan_offsets(const int* __restrict__ hist, const int* __restrict__ counts,
                             int* __restrict__ aligned_start, int* __restrict__ cursor,
                             float* __restrict__ countsf) {
    if (threadIdx.x == 0) {
        int run = 0;
        for (int c = 0; c < NC; ++c) {
            aligned_start[c] = run;
            cursor[c] = run;
            run = (run + hist[c] + 63) & ~63;
        }
    }
    if (threadIdx.x < NC) countsf[threadIdx.x] = (float)counts[threadIdx.x];
}

// initialize ALL padded slots as inert dummies (Ce=0 => msg=0) with the cid of
// the range they fall in (so every 64-group is cid-uniform).
__global__ void fill_dummy(const int* __restrict__ aligned_start,
                           float* __restrict__ ew_s, float* __restrict__ c_s,
                           int* __restrict__ src_s, int* __restrict__ cid_s) {
    int s = blockIdx.x * 256 + threadIdx.x;     // 0..PADE-1
    int lo = 0, hi = NC - 1;
    #pragma unroll
    for (int it = 0; it < 8; ++it) {            // 2^8 >= NC
        int mid = (lo + hi + 1) >> 1;
        if (aligned_start[mid] <= s) lo = mid; else hi = mid - 1;
    }
    ew_s[s] = 0.0f; c_s[s] = 0.0f; src_s[s] = 0; cid_s[s] = lo;
}

__global__ void scatter_edges(const float* __restrict__ pos, const int* __restrict__ ei,
                              const int* __restrict__ comp_id, int* __restrict__ cursor,
                              float* __restrict__ ew_s, float* __restrict__ c_s,
                              int* __restrict__ src_s, int* __restrict__ cid_s) {
    int e = blockIdx.x * 256 + threadIdx.x;
    int s = ei[e], d = ei[NEDGE + e];
    float dx = pos[3*s]   - pos[3*d];
    float dy = pos[3*s+1] - pos[3*d+1];
    float dz = pos[3*s+2] - pos[3*d+2];
    float d2 = dx*dx + dy*dy + dz*dz;
    float ew = sqrtf(d2);
    float C  = CUT / (1e-10f + d2) - 1.0f;
    int cid = comp_id[d];
    int idx = atomicAdd(&cursor[cid], 1);
    ew_s[idx] = ew; c_s[idx] = C; src_s[idx] = s; cid_s[idx] = cid;
}

// xh_all[l][n][f] = (emb[z[n]] @ cf_lin1_w[l])[f]
// block = 4 waves x 64 nodes; wave fq owns features [fq*32, fq*32+32)
__global__ __launch_bounds__(256) void xh_kernel(const float* __restrict__ emb,
                                                 const int* __restrict__ z,
                                                 const float* __restrict__ cf1,
                                                 float* __restrict__ xh_all) {
    const int lane = threadIdx.x & 63;
    const int fq = __builtin_amdgcn_readfirstlane(threadIdx.x >> 6);
    const int l = blockIdx.y;
    const int n = blockIdx.x * 64 + lane;
    const float* h = emb + z[n] * HD;
    const float* w = cf1 + l * HD * FD + fq * 32;
    float acc[32];
    #pragma unroll
    for (int j = 0; j < 32; ++j) acc[j] = 0.0f;
    #pragma unroll 1
    for (int k = 0; k < HD; k += 4) {
        float4 hk = *(const float4*)(h + k);
        const float* w0 = w + k * FD;
        #pragma unroll
        for (int j = 0; j < 32; ++j) {
            float a = acc[j];
            a = fmaf(hk.x, w0[j], a);
            a = fmaf(hk.y, w0[FD + j], a);
            a = fmaf(hk.z, w0[2 * FD + j], a);
            a = fmaf(hk.w, w0[3 * FD + j], a);
            acc[j] = a;
        }
    }
    float* o = xh_all + ((long)l * NNODES + n) * FD + fq * 32;
    #pragma unroll
    for (int j = 0; j < 32; j += 4)
        *(float4*)(o + j) = make_float4(acc[j], acc[j+1], acc[j+2], acc[j+3]);
}

__global__ void types_init(const float* __restrict__ emb, const int* __restrict__ comps_z,
                           float* __restrict__ types) {
    int c = blockIdx.x; int f = threadIdx.x;
    types[c * HD + f] = emb[comps_z[c] * HD + f];
}

// ---------- hot kernel: per-edge filter MLP + message + comp aggregation ----------
// Block = 256 threads = 4 waves over (64 edges) x (4 feature quarters).
// grid = (PADG, L). Every 64-edge group is cid-uniform by construction.
__global__ __launch_bounds__(256) void edge_kernel(
    const float* __restrict__ ew_s, const float* __restrict__ c_s,
    const int* __restrict__ src_s, const int* __restrict__ cid_s,
    const float* __restrict__ w1_, const float* __restrict__ b1_,
    const float* __restrict__ w2_, const float* __restrict__ b2_,
    const float* __restrict__ xh_all, float* __restrict__ comp_acc)
{
    __shared__ float t_lds[64 * TSTR];
    const int lane = threadIdx.x & 63;
    const int fq = __builtin_amdgcn_readfirstlane(threadIdx.x >> 6);
    const int l = blockIdx.y;
    const int e = blockIdx.x * 64 + lane;

    const float ew = ew_s[e];
    const float Ce = c_s[e];
    // fully-dummy group: all 4 waves see the same 64 edges -> uniform decision
    if (__all(Ce == 0.0f)) return;
    const int src  = src_s[e];
    const int cid  = cid_s[e];

    const float* w1 = w1_ + l * GD * FD + fq * 32;    // [g][f-quarter]
    const float* b1 = b1_ + l * FD + fq * 32;
    const float* w2 = w2_ + l * FD * FD + fq * 32;    // [fi][fo-quarter]
    const float* b2 = b2_ + l * FD + fq * 32;

    // ---- stage 1: t = ssp(edge_attr @ W1 + b1), this wave's 32 features ----
    float acc[32];
    #pragma unroll
    for (int j = 0; j < 32; ++j) acc[j] = b1[j];
    const float delta = CUT / (GD - 1);
    const float coeff = -0.5f / (delta * delta);
    #pragma unroll 2
    for (int g = 0; g < GD; ++g) {
        float dd = ew - g * delta;
        float a = __expf(coeff * dd * dd);
        const float* w1g = w1 + g * FD;
        #pragma unroll
        for (int j = 0; j < 32; ++j) acc[j] = fmaf(a, w1g[j], acc[j]);
    }
    float* trow = &t_lds[lane * TSTR + fq * 32];
    #pragma unroll
    for (int j = 0; j < 32; ++j) trow[j] = ssp(acc[j]);
    __syncthreads();

    // ---- stage 2: W[e][fo] = t[e][:] @ W2[:, fo] + b2, fo in this quarter ----
    float acc2[32];
    #pragma unroll
    for (int j = 0; j < 32; ++j) acc2[j] = b2[j];
    const float* tread = &t_lds[lane * TSTR];
    #pragma unroll 2
    for (int fi = 0; fi < FD; ++fi) {
        float tv = tread[fi];
        const float* w2r = w2 + fi * FD;
        #pragma unroll
        for (int j = 0; j < 32; ++j) acc2[j] = fmaf(tv, w2r[j], acc2[j]);
    }

    // ---- stage 3: msg = xh[src] * W * C; wave butterfly; 1 atomic/feature ----
    const float* xh = xh_all + ((long)l * NNODES + src) * FD + fq * 32;
    float msg[32];
    #pragma unroll
    for (int j = 0; j < 32; j += 4) {
        float4 xv = *(const float4*)(xh + j);
        msg[j]     = xv.x * acc2[j]     * Ce;
        msg[j + 1] = xv.y * acc2[j + 1] * Ce;
        msg[j + 2] = xv.z * acc2[j + 2] * Ce;
        msg[j + 3] = xv.w * acc2[j + 3] * Ce;
    }

    float* cacc = comp_acc + (l * NC + cid) * FD + fq * 32;
    #pragma unroll
    for (int j = 0; j < 32; ++j) {
        float m = msg[j];
        #pragma unroll
        for (int s = 32; s > 0; s >>= 1) m += __shfl_xor(m, s);
        if (lane == j) atomicAdd(&cacc[j], m);     // spread over lanes 0..31
    }
}

// ---------- per-component update: x = ssp(comp@cf2+b)@intw+b; types += x ----------
__global__ __launch_bounds__(128) void comp_kernel(
    const float* __restrict__ comp_acc, const float* __restrict__ countsf,
    const float* __restrict__ cf2w, const float* __restrict__ cf2b,
    const float* __restrict__ intw, const float* __restrict__ intb,
    float* __restrict__ types)
{
    int c = blockIdx.x, l = blockIdx.y, f = threadIdx.x;
    __shared__ float comp[FD];
    __shared__ float sx[FD];
    comp[f] = comp_acc[(l * NC + c) * FD + f] / countsf[c];
    __syncthreads();
    float acc = cf2b[l * HD + f];
    const float* w = cf2w + l * FD * HD;
    #pragma unroll 8
    for (int k = 0; k < FD; ++k) acc = fmaf(comp[k], w[k * HD + f], acc);
    sx[f] = ssp(acc);
    __syncthreads();
    float acc2 = intb[l * HD + f];
    const float* wi = intw + l * HD * HD;
    #pragma unroll 8
    for (int k = 0; k < HD; ++k) acc2 = fmaf(sx[k], wi[k * HD + f], acc2);
    atomicAdd(&types[c * HD + f], acc2);
}

// ---------- readout: out[b] = sum_c per_comp(c) ----------
__global__ __launch_bounds__(64) void readout_kernel(
    const float* __restrict__ types, const float* __restrict__ w1,
    const float* __restrict__ b1, const float* __restrict__ w2,
    const float* __restrict__ b2, float* __restrict__ out)
{
    int b = blockIdx.x, lane = threadIdx.x;
    float sum = 0.0f;
    for (int cc = 0; cc < NELEM; ++cc) {
        int c = b * NELEM + cc;
        float acc = b1[lane];
        const float* tr = types + c * HD;
        #pragma unroll 8
        for (int k = 0; k < HD; ++k) acc = fmaf(tr[k], w1[k * 64 + lane], acc);
        sum += ssp(acc) * w2[lane];
    }
    #pragma unroll
    for (int s = 32; s > 0; s >>= 1) sum += __shfl_xor(sum, s);
    if (lane == 0) out[b] = sum + (float)NELEM * b2[0];
}

extern "C" void kernel_launch(void* const* d_in, const int* in_sizes, int n_in,
                              void* d_out, int out_size, void* d_ws, size_t ws_size,
                              hipStream_t stream) {
    (void)in_sizes; (void)n_in; (void)out_size; (void)ws_size;
    const float* pos     = (const float*)d_in[0];
    const float* emb     = (const float*)d_in[1];
    const float* mlp_w1  = (const float*)d_in[2];
    const float* mlp_b1  = (const float*)d_in[3];
    const float* mlp_w2  = (const float*)d_in[4];
    const float* mlp_b2  = (const float*)d_in[5];
    const float* cf1     = (const float*)d_in[6];
    const float* cf2w    = (const float*)d_in[7];
    const float* cf2b    = (const float*)d_in[8];
    const float* intw    = (const float*)d_in[9];
    const float* intb    = (const float*)d_in[10];
    const float* ow1     = (const float*)d_in[11];
    const float* ob1     = (const float*)d_in[12];
    const float* ow2     = (const float*)d_in[13];
    const float* ob2     = (const float*)d_in[14];
    const int*   z       = (const int*)d_in[15];
    const int*   comp_id = (const int*)d_in[16];
    const int*   ei      = (const int*)d_in[17];
    const int*   comps_z = (const int*)d_in[18];
    float* out = (float*)d_out;

    char* ws = (char*)d_ws;
    size_t off = 0;
    auto alloc = [&](size_t bytes) -> void* {
        void* p = ws + off;
        off += (bytes + 255) & ~(size_t)255;
        return p;
    };
    // zeroed prefix: comp_acc | hist | counts
    float* comp_acc = (float*)alloc((size_t)LL * NC * FD * 4);
    int*   hist     = (int*)  alloc(NC * 4);
    int*   counts   = (int*)  alloc(NC * 4);
    size_t zero_bytes = off;
    int*   astart   = (int*)  alloc(NC * 4);
    int*   cursor   = (int*)  alloc(NC * 4);
    float* countsf  = (float*)alloc(NC * 4);
    float* ew_s     = (float*)alloc((size_t)PADE * 4);
    float* c_s      = (float*)alloc((size_t)PADE * 4);
    int*   src_s    = (int*)  alloc((size_t)PADE * 4);
    int*   cid_s    = (int*)  alloc((size_t)PADE * 4);
    float* xh_all   = (float*)alloc((size_t)LL * NNODES * FD * 4);
    float* types    = (float*)alloc((size_t)NC * HD * 4);

    hipMemsetAsync(d_ws, 0, zero_bytes, stream);

    hist_edges   <<<NEDGE / 256, 256, 0, stream>>>(ei, comp_id, hist);
    count_nodes  <<<NNODES / 256, 256, 0, stream>>>(comp_id, counts);
    scan_offsets <<<1, 256, 0, stream>>>(hist, counts, astart, cursor, countsf);
    fill_dummy   <<<PADE / 256, 256, 0, stream>>>(astart, ew_s, c_s, src_s, cid_s);
    scatter_edges<<<NEDGE / 256, 256, 0, stream>>>(pos, ei, comp_id, cursor,
                                                   ew_s, c_s, src_s, cid_s);
    xh_kernel    <<<dim3(NNODES / 64, LL), 256, 0, stream>>>(emb, z, cf1, xh_all);
    types_init   <<<NC, HD, 0, stream>>>(emb, comps_z, types);
    edge_kernel  <<<dim3(PADG, LL), 256, 0, stream>>>(ew_s, c_s, src_s, cid_s,
                                                      mlp_w1, mlp_b1, mlp_w2, mlp_b2,
                                                      xh_all, comp_acc);
    comp_kernel  <<<dim3(NC, LL), 128, 0, stream>>>(comp_acc, countsf, cf2w, cf2b,
                                                    intw, intb, types);
    readout_kernel<<<NGRAPH, 64, 0, stream>>>(types, ow1, ob1, ow2, ob2, out);
}

// Round 5
// 400.285 us; speedup vs baseline: 3.9999x; 1.9615x over previous
//
#include <hip/hip_runtime.h>

// HeaNet: SchNet-like GNN on MI355X.
// R5: MFMA (f32_16x16x32_f16) for both edge-MLP GEMMs.
//  - GEMM-1: T[64x128] = G[64x64] @ W1p[64x128]  (K padded 50->64 with zeros)
//    A computed in-register in A-frag layout (A[m=lane&15][k=quad*8+j], m120-verified);
//    B pre-swizzled to fragment order by make_frags (coalesced dwordx4 loads);
//    bias b1 folded into C-operand init.
//  - T -> ssp -> f16 -> LDS (pitch 136 halfs = 272B: rows 4 banks apart, b128-clean)
//  - GEMM-2: Wm[64x128] = T @ W2, b2 in C-init; epilogue: *Ce, *xh gather,
//    in-register M-reduction + cross-quad butterfly -> 32 atomics/wave (as R4).
// cid-padding from R4 kept: every 64-edge group is cid-uniform; dummies Ce=0.

#define NNODES 8192
#define NGRAPH 32
#define NPER   256
#define NELEM  5
#define NEDGE  131072
#define HD     128
#define FD     128
#define GD     50
#define LL     6
#define NC     160
#define CUT    10.0f
#define LOG2_  0.69314718055994531f

#define PADE   141312
#define PADG   (PADE / 64)       // 2208 edge-groups
#define TPITCH 136               // LDS T pitch in halfs (272 B)

#define W1F_ELEMS (LL * 2 * 8 * 64 * 8)   // 49152
#define W2F_ELEMS (LL * 4 * 8 * 64 * 8)   // 98304

typedef _Float16 half8 __attribute__((ext_vector_type(8)));
typedef float floatx4 __attribute__((ext_vector_type(4)));

__device__ __forceinline__ float ssp(float x) {
    float m = fmaxf(x, 0.0f);
    float z = __expf(-fabsf(x));
    return m + __logf(1.0f + z) - LOG2_;
}

// ---------- setup kernels ----------

// fused: per-cid edge histogram + per-cid node counts
__global__ void prep_counts(const int* __restrict__ ei, const int* __restrict__ comp_id,
                            int* __restrict__ hist, int* __restrict__ counts) {
    __shared__ int lh[NC];
    int tid = threadIdx.x;
    if (tid < NC) lh[tid] = 0;
    __syncthreads();
    int e = blockIdx.x * 256 + tid;
    atomicAdd(&lh[comp_id[ei[NEDGE + e]]], 1);
    if (e < NNODES) atomicAdd(&counts[comp_id[e]], 1);
    __syncthreads();
    if (tid < NC) atomicAdd(&hist[tid], lh[tid]);
}

__global__ void scan_offsets(const int* __restrict__ hist, const int* __restrict__ counts,
                             int* __restrict__ aligned_start, int* __restrict__ cursor,
                             float* __restrict__ countsf) {
    if (threadIdx.x == 0) {
        int run = 0;
        for (int c = 0; c < NC; ++c) {
            aligned_start[c] = run;
            cursor[c] = run;
            run = (run + hist[c] + 63) & ~63;
        }
    }
    if (threadIdx.x < NC) countsf[threadIdx.x] = (float)counts[threadIdx.x];
}

__global__ void fill_dummy(const int* __restrict__ aligned_start,
                           float* __restrict__ ew_s, float* __restrict__ c_s,
                           int* __restrict__ src_s, int* __restrict__ cid_s) {
    int s = blockIdx.x * 256 + threadIdx.x;
    int lo = 0, hi = NC - 1;
    #pragma unroll
    for (int it = 0; it < 8; ++it) {
        int mid = (lo + hi + 1) >> 1;
        if (aligned_start[mid] <= s) lo = mid; else hi = mid - 1;
    }
    ew_s[s] = 0.0f; c_s[s] = 0.0f; src_s[s] = 0; cid_s[s] = lo;
}

__global__ void scatter_edges(const float* __restrict__ pos, const int* __restrict__ ei,
                              const int* __restrict__ comp_id, int* __restrict__ cursor,
                              float* __restrict__ ew_s, float* __restrict__ c_s,
                              int* __restrict__ src_s, int* __restrict__ cid_s) {
    int e = blockIdx.x * 256 + threadIdx.x;
    int s = ei[e], d = ei[NEDGE + e];
    float dx = pos[3*s]   - pos[3*d];
    float dy = pos[3*s+1] - pos[3*d+1];
    float dz = pos[3*s+2] - pos[3*d+2];
    float d2 = dx*dx + dy*dy + dz*dz;
    float ew = sqrtf(d2);
    float C  = CUT / (1e-10f + d2) - 1.0f;
    int cid = comp_id[d];
    int idx = atomicAdd(&cursor[cid], 1);
    ew_s[idx] = ew; c_s[idx] = C; src_s[idx] = s; cid_s[idx] = cid;
}

// Pre-swizzle W1 (K-padded 50->64, zeros) and W2 into B-fragment order:
// frag[l][kb][tcg][lane][j] = W[k = kb*32 + (lane>>4)*8 + j][col = tcg*16 + (lane&15)]
__global__ void make_frags(const float* __restrict__ w1, const float* __restrict__ w2,
                           _Float16* __restrict__ w1f, _Float16* __restrict__ w2f) {
    int idx = blockIdx.x * 256 + threadIdx.x;     // 576*256 = W1F+W2F exactly
    if (idx < W1F_ELEMS) {
        int j = idx & 7, lane = (idx >> 3) & 63, tcg = (idx >> 9) & 7;
        int kb = (idx >> 12) & 1, l = idx >> 13;
        int k = kb * 32 + (lane >> 4) * 8 + j;
        int col = tcg * 16 + (lane & 15);
        float v = (k < GD) ? w1[(l * GD + k) * FD + col] : 0.0f;
        w1f[idx] = (_Float16)v;
    } else {
        int id2 = idx - W1F_ELEMS;
        int j = id2 & 7, lane = (id2 >> 3) & 63, tcg = (id2 >> 9) & 7;
        int kb = (id2 >> 12) & 3, l = id2 >> 14;
        int k = kb * 32 + (lane >> 4) * 8 + j;
        int col = tcg * 16 + (lane & 15);
        w2f[id2] = (_Float16)w2[(l * FD + k) * FD + col];
    }
}

// xh_all[l][n][f] = (emb[z[n]] @ cf_lin1_w[l])[f]
__global__ __launch_bounds__(256) void xh_kernel(const float* __restrict__ emb,
                                                 const int* __restrict__ z,
                                                 const float* __restrict__ cf1,
                                                 float* __restrict__ xh_all) {
    const int lane = threadIdx.x & 63;
    const int fq = __builtin_amdgcn_readfirstlane(threadIdx.x >> 6);
    const int l = blockIdx.y;
    const int n = blockIdx.x * 64 + lane;
    const float* h = emb + z[n] * HD;
    const float* w = cf1 + l * HD * FD + fq * 32;
    float acc[32];
    #pragma unroll
    for (int j = 0; j < 32; ++j) acc[j] = 0.0f;
    #pragma unroll 1
    for (int k = 0; k < HD; k += 4) {
        float4 hk = *(const float4*)(h + k);
        const float* w0 = w + k * FD;
        #pragma unroll
        for (int j = 0; j < 32; ++j) {
            float a = acc[j];
            a = fmaf(hk.x, w0[j], a);
            a = fmaf(hk.y, w0[FD + j], a);
            a = fmaf(hk.z, w0[2 * FD + j], a);
            a = fmaf(hk.w, w0[3 * FD + j], a);
            acc[j] = a;
        }
    }
    float* o = xh_all + ((long)l * NNODES + n) * FD + fq * 32;
    #pragma unroll
    for (int j = 0; j < 32; j += 4)
        *(float4*)(o + j) = make_float4(acc[j], acc[j+1], acc[j+2], acc[j+3]);
}

__global__ void types_init(const float* __restrict__ emb, const int* __restrict__ comps_z,
                           float* __restrict__ types) {
    int c = blockIdx.x; int f = threadIdx.x;
    types[c * HD + f] = emb[comps_z[c] * HD + f];
}

// ---------- hot kernel: MFMA edge MLP + message + comp aggregation ----------
// Block = 256 threads = 4 waves; block handles 64 edges x 128 features.
// Wave fq owns cols [fq*32, fq*32+32) = tile-cols {fq*2, fq*2+1}.
__global__ __launch_bounds__(256, 4) void edge_kernel(
    const float* __restrict__ ew_s, const float* __restrict__ c_s,
    const int* __restrict__ src_s, const int* __restrict__ cid_s,
    const _Float16* __restrict__ w1f, const float* __restrict__ b1_,
    const _Float16* __restrict__ w2f, const float* __restrict__ b2_,
    const float* __restrict__ xh_all, float* __restrict__ comp_acc)
{
    __shared__ __align__(16) _Float16 tb[64 * TPITCH];
    __shared__ float ew_l[64];
    __shared__ float ce_l[64];
    __shared__ int   src_l[64];

    const int tid  = threadIdx.x;
    const int lane = tid & 63;
    const int l15  = lane & 15;
    const int quad = lane >> 4;
    const int fq   = __builtin_amdgcn_readfirstlane(tid >> 6);
    const int l    = blockIdx.y;
    const int g0   = blockIdx.x * 64;

    if (tid < 64) {
        ew_l[tid]  = ew_s[g0 + tid];
        ce_l[tid]  = c_s[g0 + tid];
        src_l[tid] = src_s[g0 + tid];
    }
    const int cid = cid_s[g0];                 // group-uniform by construction
    const int colbase = fq * 32 + l15;
    const float b1c0 = b1_[l * FD + colbase];
    const float b1c1 = b1_[l * FD + colbase + 16];
    const float b2c0 = b2_[l * FD + colbase];
    const float b2c1 = b2_[l * FD + colbase + 16];
    __syncthreads();

    const float delta = CUT / (GD - 1);
    const float coeff = -0.5f / (delta * delta);

    // ---- GEMM-1: T = G @ W1p (+b1 via C-init) ----
    floatx4 accT[4][2];
    #pragma unroll
    for (int tr = 0; tr < 4; ++tr) {
        accT[tr][0] = (floatx4){b1c0, b1c0, b1c0, b1c0};
        accT[tr][1] = (floatx4){b1c1, b1c1, b1c1, b1c1};
    }
    const half8* w1fp = (const half8*)w1f;
    #pragma unroll
    for (int kb = 0; kb < 2; ++kb) {
        half8 bf0 = w1fp[((l * 2 + kb) * 8 + fq * 2 + 0) * 64 + lane];
        half8 bf1 = w1fp[((l * 2 + kb) * 8 + fq * 2 + 1) * 64 + lane];
        const int kbase = kb * 32 + quad * 8;
        #pragma unroll
        for (int tr = 0; tr < 4; ++tr) {
            float ewr = ew_l[tr * 16 + l15];
            half8 af;
            #pragma unroll
            for (int j = 0; j < 8; ++j) {
                float dd = ewr - (kbase + j) * delta;
                af[j] = (_Float16)__expf(coeff * dd * dd);
            }
            accT[tr][0] = __builtin_amdgcn_mfma_f32_16x16x32_f16(af, bf0, accT[tr][0], 0, 0, 0);
            accT[tr][1] = __builtin_amdgcn_mfma_f32_16x16x32_f16(af, bf1, accT[tr][1], 0, 0, 0);
        }
    }
    // ssp + store T to LDS (C-layout scatter: row = tr*16+quad*4+r, col = tile col)
    #pragma unroll
    for (int tr = 0; tr < 4; ++tr) {
        #pragma unroll
        for (int tcl = 0; tcl < 2; ++tcl) {
            #pragma unroll
            for (int r = 0; r < 4; ++r) {
                float v = ssp(accT[tr][tcl][r]);
                tb[(tr * 16 + quad * 4 + r) * TPITCH + fq * 32 + tcl * 16 + l15] = (_Float16)v;
            }
        }
    }
    __syncthreads();

    // ---- GEMM-2: Wm = T @ W2 (+b2 via C-init) ----
    floatx4 accW[4][2];
    #pragma unroll
    for (int tr = 0; tr < 4; ++tr) {
        accW[tr][0] = (floatx4){b2c0, b2c0, b2c0, b2c0};
        accW[tr][1] = (floatx4){b2c1, b2c1, b2c1, b2c1};
    }
    const half8* w2fp = (const half8*)w2f;
    #pragma unroll
    for (int kb = 0; kb < 4; ++kb) {
        half8 bf0 = w2fp[((l * 4 + kb) * 8 + fq * 2 + 0) * 64 + lane];
        half8 bf1 = w2fp[((l * 4 + kb) * 8 + fq * 2 + 1) * 64 + lane];
        #pragma unroll
        for (int tr = 0; tr < 4; ++tr) {
            half8 af = *(const half8*)&tb[(tr * 16 + l15) * TPITCH + kb * 32 + quad * 8];
            accW[tr][0] = __builtin_amdgcn_mfma_f32_16x16x32_f16(af, bf0, accW[tr][0], 0, 0, 0);
            accW[tr][1] = __builtin_amdgcn_mfma_f32_16x16x32_f16(af, bf1, accW[tr][1], 0, 0, 0);
        }
    }

    // ---- epilogue: msg = xh[src] * Wm * Ce; reduce M in-register + cross-quad ----
    float s0 = 0.0f, s1 = 0.0f;
    #pragma unroll
    for (int tr = 0; tr < 4; ++tr) {
        #pragma unroll
        for (int r = 0; r < 4; ++r) {
            const int e = tr * 16 + quad * 4 + r;      // broadcast LDS reads in-quad
            const float ce = ce_l[e];
            const float* xr = xh_all + ((long)l * NNODES + src_l[e]) * FD + colbase;
            s0 += accW[tr][0][r] * ce * xr[0];
            s1 += accW[tr][1][r] * ce * xr[16];
        }
    }
    s0 += __shfl_xor(s0, 16); s0 += __shfl_xor(s0, 32);
    s1 += __shfl_xor(s1, 16); s1 += __shfl_xor(s1, 32);
    float* cacc = comp_acc + (l * NC + cid) * FD + fq * 32;
    if (quad == 0) {
        atomicAdd(&cacc[l15],      s0);
        atomicAdd(&cacc[l15 + 16], s1);
    }
}

// ---------- per-component update: x = ssp(comp@cf2+b)@intw+b; types += x ----------
__global__ __launch_bounds__(128) void comp_kernel(
    const float* __restrict__ comp_acc, const float* __restrict__ countsf,
    const float* __restrict__ cf2w, const float* __restrict__ cf2b,
    const float* __restrict__ intw, const float* __restrict__ intb,
    float* __restrict__ types)
{
    int c = blockIdx.x, l = blockIdx.y, f = threadIdx.x;
    __shared__ float comp[FD];
    __shared__ float sx[FD];
    comp[f] = comp_acc[(l * NC + c) * FD + f] / countsf[c];
    __syncthreads();
    float acc = cf2b[l * HD + f];
    const float* w = cf2w + l * FD * HD;
    #pragma unroll 8
    for (int k = 0; k < FD; ++k) acc = fmaf(comp[k], w[k * HD + f], acc);
    sx[f] = ssp(acc);
    __syncthreads();
    float acc2 = intb[l * HD + f];
    const float* wi = intw + l * HD * HD;
    #pragma unroll 8
    for (int k = 0; k < HD; ++k) acc2 = fmaf(sx[k], wi[k * HD + f], acc2);
    atomicAdd(&types[c * HD + f], acc2);
}

// ---------- readout ----------
__global__ __launch_bounds__(64) void readout_kernel(
    const float* __restrict__ types, const float* __restrict__ w1,
    const float* __restrict__ b1, const float* __restrict__ w2,
    const float* __restrict__ b2, float* __restrict__ out)
{
    int b = blockIdx.x, lane = threadIdx.x;
    float sum = 0.0f;
    for (int cc = 0; cc < NELEM; ++cc) {
        int c = b * NELEM + cc;
        float acc = b1[lane];
        const float* tr = types + c * HD;
        #pragma unroll 8
        for (int k = 0; k < HD; ++k) acc = fmaf(tr[k], w1[k * 64 + lane], acc);
        sum += ssp(acc) * w2[lane];
    }
    #pragma unroll
    for (int s = 32; s > 0; s >>= 1) sum += __shfl_xor(sum, s);
    if (lane == 0) out[b] = sum + (float)NELEM * b2[0];
}

extern "C" void kernel_launch(void* const* d_in, const int* in_sizes, int n_in,
                              void* d_out, int out_size, void* d_ws, size_t ws_size,
                              hipStream_t stream) {
    (void)in_sizes; (void)n_in; (void)out_size; (void)ws_size;
    const float* pos     = (const float*)d_in[0];
    const float* emb     = (const float*)d_in[1];
    const float* mlp_w1  = (const float*)d_in[2];
    const float* mlp_b1  = (const float*)d_in[3];
    const float* mlp_w2  = (const float*)d_in[4];
    const float* mlp_b2  = (const float*)d_in[5];
    const float* cf1     = (const float*)d_in[6];
    const float* cf2w    = (const float*)d_in[7];
    const float* cf2b    = (const float*)d_in[8];
    const float* intw    = (const float*)d_in[9];
    const float* intb    = (const float*)d_in[10];
    const float* ow1     = (const float*)d_in[11];
    const float* ob1     = (const float*)d_in[12];
    const float* ow2     = (const float*)d_in[13];
    const float* ob2     = (const float*)d_in[14];
    const int*   z       = (const int*)d_in[15];
    const int*   comp_id = (const int*)d_in[16];
    const int*   ei      = (const int*)d_in[17];
    const int*   comps_z = (const int*)d_in[18];
    float* out = (float*)d_out;

    char* ws = (char*)d_ws;
    size_t off = 0;
    auto alloc = [&](size_t bytes) -> void* {
        void* p = ws + off;
        off += (bytes + 255) & ~(size_t)255;
        return p;
    };
    // zeroed prefix: comp_acc | hist | counts
    float* comp_acc = (float*)alloc((size_t)LL * NC * FD * 4);
    int*   hist     = (int*)  alloc(NC * 4);
    int*   counts   = (int*)  alloc(NC * 4);
    size_t zero_bytes = off;
    int*   astart   = (int*)  alloc(NC * 4);
    int*   cursor   = (int*)  alloc(NC * 4);
    float* countsf  = (float*)alloc(NC * 4);
    float* ew_s     = (float*)alloc((size_t)PADE * 4);
    float* c_s      = (float*)alloc((size_t)PADE * 4);
    int*   src_s    = (int*)  alloc((size_t)PADE * 4);
    int*   cid_s    = (int*)  alloc((size_t)PADE * 4);
    float* xh_all   = (float*)alloc((size_t)LL * NNODES * FD * 4);
    float* types    = (float*)alloc((size_t)NC * HD * 4);
    _Float16* w1f   = (_Float16*)alloc((size_t)W1F_ELEMS * 2);
    _Float16* w2f   = (_Float16*)alloc((size_t)W2F_ELEMS * 2);

    hipMemsetAsync(d_ws, 0, zero_bytes, stream);

    prep_counts  <<<NEDGE / 256, 256, 0, stream>>>(ei, comp_id, hist, counts);
    scan_offsets <<<1, 256, 0, stream>>>(hist, counts, astart, cursor, countsf);
    fill_dummy   <<<PADE / 256, 256, 0, stream>>>(astart, ew_s, c_s, src_s, cid_s);
    scatter_edges<<<NEDGE / 256, 256, 0, stream>>>(pos, ei, comp_id, cursor,
                                                   ew_s, c_s, src_s, cid_s);
    make_frags   <<<(W1F_ELEMS + W2F_ELEMS) / 256, 256, 0, stream>>>(mlp_w1, mlp_w2, w1f, w2f);
    xh_kernel    <<<dim3(NNODES / 64, LL), 256, 0, stream>>>(emb, z, cf1, xh_all);
    types_init   <<<NC, HD, 0, stream>>>(emb, comps_z, types);
    edge_kernel  <<<dim3(PADG, LL), 256, 0, stream>>>(ew_s, c_s, src_s, cid_s,
                                                      w1f, mlp_b1, w2f, mlp_b2,
                                                      xh_all, comp_acc);
    comp_kernel  <<<dim3(NC, LL), 128, 0, stream>>>(comp_acc, countsf, cf2w, cf2b,
                                                    intw, intb, types);
    readout_kernel<<<NGRAPH, 64, 0, stream>>>(types, ow1, ob1, ow2, ob2, out);
}

// Round 6
// 330.249 us; speedup vs baseline: 4.8482x; 1.2121x over previous
//
#include <hip/hip_runtime.h>

// HeaNet R6:
//  - xh_z table: z=comps_z[comp_id] has <100 distinct values -> per-z xh rows
//    (6x100x128, 307 KB) replace the 6x8192x128 xh_all GEMM + 25MB refetch.
//  - edge_kernel stages gaussian G[64x64] (f16) in LDS once per block:
//    16 exps/thread (was 64, 4x wave redundancy); A-frags via ds_read_b128.
//    G aliases the T buffer (barrier-separated) -> LDS stays ~18 KB.
//  - parallel scan, per-cid fill_dummy, types_init folded into readout.

#define NNODES 8192
#define NGRAPH 32
#define NELEM  5
#define NEDGE  131072
#define HD     128
#define FD     128
#define GD     50
#define LL     6
#define NC     160
#define NZ     100
#define CUT    10.0f
#define LOG2_  0.69314718055994531f

#define PADE   141312
#define PADG   (PADE / 64)
#define GPITCH 72                // halfs per G row (b128-aligned, balanced banks)
#define TPITCH 136               // halfs per T row

#define W1F_ELEMS (LL * 2 * 8 * 64 * 8)   // 49152
#define W2F_ELEMS (LL * 4 * 8 * 64 * 8)   // 98304

typedef _Float16 half8 __attribute__((ext_vector_type(8)));
typedef float floatx4 __attribute__((ext_vector_type(4)));

__device__ __forceinline__ float ssp(float x) {
    float m = fmaxf(x, 0.0f);
    float z = __expf(-fabsf(x));
    return m + __logf(1.0f + z) - LOG2_;
}

// ---------- setup ----------

__global__ void prep_counts(const int* __restrict__ ei, const int* __restrict__ comp_id,
                            int* __restrict__ hist, int* __restrict__ counts) {
    __shared__ int lh[NC];
    int tid = threadIdx.x;
    if (tid < NC) lh[tid] = 0;
    __syncthreads();
    int e = blockIdx.x * 256 + tid;
    atomicAdd(&lh[comp_id[ei[NEDGE + e]]], 1);
    if (e < NNODES) atomicAdd(&counts[comp_id[e]], 1);
    __syncthreads();
    if (tid < NC) atomicAdd(&hist[tid], lh[tid]);
}

// parallel exclusive scan of ceil64(hist) (run stays 64-aligned so the
// reference recurrence run=(run+h+63)&~63 equals prefix of ceil64(h))
__global__ void scan_offsets(const int* __restrict__ hist, const int* __restrict__ counts,
                             int* __restrict__ astart, int* __restrict__ cursor,
                             float* __restrict__ countsf) {
    __shared__ int sbuf[256];
    int tid = threadIdx.x;
    int v = (tid < NC) ? ((hist[tid] + 63) & ~63) : 0;
    sbuf[tid] = v;
    __syncthreads();
    for (int ofs = 1; ofs < 256; ofs <<= 1) {
        int x = (tid >= ofs) ? sbuf[tid - ofs] : 0;
        __syncthreads();
        sbuf[tid] += x;
        __syncthreads();
    }
    if (tid < NC) {
        int excl = sbuf[tid] - v;
        astart[tid] = excl;
        cursor[tid] = excl;
        countsf[tid] = (float)counts[tid];
    }
}

// fill only the pad tail of each cid range (plus the global trailing region)
__global__ void fill_dummy(const int* __restrict__ astart, const int* __restrict__ hist,
                           float* __restrict__ ew_s, float* __restrict__ c_s,
                           int* __restrict__ zsrc_s, int* __restrict__ cid_s) {
    int c = blockIdx.x;
    int start = astart[c], h = hist[c];
    int end = (start + h + 63) & ~63;
    if (c == NC - 1) end = PADE;
    for (int s = start + h + threadIdx.x; s < end; s += 256) {
        ew_s[s] = 0.0f; c_s[s] = 0.0f; zsrc_s[s] = 0; cid_s[s] = c;
    }
}

__global__ void scatter_edges(const float* __restrict__ pos, const int* __restrict__ ei,
                              const int* __restrict__ comp_id, const int* __restrict__ z,
                              int* __restrict__ cursor,
                              float* __restrict__ ew_s, float* __restrict__ c_s,
                              int* __restrict__ zsrc_s, int* __restrict__ cid_s) {
    int e = blockIdx.x * 256 + threadIdx.x;
    int s = ei[e], d = ei[NEDGE + e];
    float dx = pos[3*s]   - pos[3*d];
    float dy = pos[3*s+1] - pos[3*d+1];
    float dz = pos[3*s+2] - pos[3*d+2];
    float d2 = dx*dx + dy*dy + dz*dz;
    float ew = sqrtf(d2);
    float C  = CUT / (1e-10f + d2) - 1.0f;
    int cid = comp_id[d];
    int idx = atomicAdd(&cursor[cid], 1);
    ew_s[idx] = ew; c_s[idx] = C; zsrc_s[idx] = z[s]; cid_s[idx] = cid;
}

// B-fragment pre-swizzle (unchanged from R5; verified by R5 pass)
__global__ void make_frags(const float* __restrict__ w1, const float* __restrict__ w2,
                           _Float16* __restrict__ w1f, _Float16* __restrict__ w2f) {
    int idx = blockIdx.x * 256 + threadIdx.x;
    if (idx < W1F_ELEMS) {
        int j = idx & 7, lane = (idx >> 3) & 63, tcg = (idx >> 9) & 7;
        int kb = (idx >> 12) & 1, l = idx >> 13;
        int k = kb * 32 + (lane >> 4) * 8 + j;
        int col = tcg * 16 + (lane & 15);
        float v = (k < GD) ? w1[(l * GD + k) * FD + col] : 0.0f;
        w1f[idx] = (_Float16)v;
    } else {
        int id2 = idx - W1F_ELEMS;
        int j = id2 & 7, lane = (id2 >> 3) & 63, tcg = (id2 >> 9) & 7;
        int kb = (id2 >> 12) & 3, l = id2 >> 14;
        int k = kb * 32 + (lane >> 4) * 8 + j;
        int col = tcg * 16 + (lane & 15);
        w2f[id2] = (_Float16)w2[(l * FD + k) * FD + col];
    }
}

// xh_z[l][zv][f] = (emb[zv] @ cf1[l])[f], zv in [0,100)
__global__ __launch_bounds__(256) void xhz_kernel(const float* __restrict__ emb,
                                                  const float* __restrict__ cf1,
                                                  float* __restrict__ xh_z) {
    int l = blockIdx.y;
    int zv = blockIdx.x * 2 + (threadIdx.x >> 7);   // 50 blocks * 2 = 100 exactly
    int f = threadIdx.x & 127;
    const float* h = emb + zv * HD;                 // wave-uniform -> s_loads
    const float* w = cf1 + l * HD * FD;
    float acc = 0.0f;
    #pragma unroll 8
    for (int k = 0; k < HD; ++k) acc = fmaf(h[k], w[k * FD + f], acc);
    xh_z[(l * NZ + zv) * FD + f] = acc;
}

// ---------- hot kernel ----------
__global__ __launch_bounds__(256, 4) void edge_kernel(
    const float* __restrict__ ew_s, const float* __restrict__ c_s,
    const int* __restrict__ zsrc_s, const int* __restrict__ cid_s,
    const _Float16* __restrict__ w1f, const float* __restrict__ b1_,
    const _Float16* __restrict__ w2f, const float* __restrict__ b2_,
    const float* __restrict__ xh_z, float* __restrict__ comp_acc)
{
    __shared__ __align__(16) _Float16 smem[64 * TPITCH];   // G (64*72) then T (64*136)
    __shared__ float ce_l[64];
    __shared__ int   zs_l[64];

    const int tid  = threadIdx.x;
    const int lane = tid & 63;
    const int l15  = lane & 15;
    const int quad = lane >> 4;
    const int fq   = __builtin_amdgcn_readfirstlane(tid >> 6);
    const int l    = blockIdx.y;
    const int g0   = blockIdx.x * 64;

    const float delta = CUT / (GD - 1);
    const float coeff = -0.5f / (delta * delta);

    const float ce = c_s[g0 + lane];
    if (__all(ce == 0.0f)) return;                 // fully-dummy group
    if (tid < 64) {
        ce_l[tid] = ce;
        zs_l[tid] = zsrc_s[g0 + tid];
    }
    const int cid = cid_s[g0];                     // group-uniform by construction
    const int colbase = fq * 32 + l15;
    const float b1c0 = b1_[l * FD + colbase];
    const float b1c1 = b1_[l * FD + colbase + 16];
    const float b2c0 = b2_[l * FD + colbase];
    const float b2c1 = b2_[l * FD + colbase + 16];

    // ---- stage G[row][k] in LDS: thread (row=lane, kg=fq) computes 16 exps ----
    {
        const float ewr = ew_s[g0 + lane];
        half8 ga, gb;
        #pragma unroll
        for (int i = 0; i < 8; ++i) {
            float d0 = ewr - (fq * 16 + i) * delta;
            float d1 = ewr - (fq * 16 + 8 + i) * delta;
            ga[i] = (_Float16)__expf(coeff * d0 * d0);
            gb[i] = (_Float16)__expf(coeff * d1 * d1);
        }
        *(half8*)&smem[lane * GPITCH + fq * 16]     = ga;
        *(half8*)&smem[lane * GPITCH + fq * 16 + 8] = gb;
    }
    __syncthreads();

    // ---- GEMM-1: T = G @ W1p (+b1 via C-init) ----
    floatx4 accT[4][2];
    #pragma unroll
    for (int tr = 0; tr < 4; ++tr) {
        accT[tr][0] = (floatx4){b1c0, b1c0, b1c0, b1c0};
        accT[tr][1] = (floatx4){b1c1, b1c1, b1c1, b1c1};
    }
    const half8* w1fp = (const half8*)w1f;
    #pragma unroll
    for (int kb = 0; kb < 2; ++kb) {
        half8 bf0 = w1fp[((l * 2 + kb) * 8 + fq * 2 + 0) * 64 + lane];
        half8 bf1 = w1fp[((l * 2 + kb) * 8 + fq * 2 + 1) * 64 + lane];
        #pragma unroll
        for (int tr = 0; tr < 4; ++tr) {
            half8 af = *(const half8*)&smem[(tr * 16 + l15) * GPITCH + kb * 32 + quad * 8];
            accT[tr][0] = __builtin_amdgcn_mfma_f32_16x16x32_f16(af, bf0, accT[tr][0], 0, 0, 0);
            accT[tr][1] = __builtin_amdgcn_mfma_f32_16x16x32_f16(af, bf1, accT[tr][1], 0, 0, 0);
        }
    }
    __syncthreads();                                // all G reads done before T overwrites

    // ssp + store T (C-layout scatter)
    #pragma unroll
    for (int tr = 0; tr < 4; ++tr) {
        #pragma unroll
        for (int tcl = 0; tcl < 2; ++tcl) {
            #pragma unroll
            for (int r = 0; r < 4; ++r) {
                float v = ssp(accT[tr][tcl][r]);
                smem[(tr * 16 + quad * 4 + r) * TPITCH + fq * 32 + tcl * 16 + l15] = (_Float16)v;
            }
        }
    }
    __syncthreads();

    // ---- GEMM-2: Wm = T @ W2 (+b2 via C-init) ----
    floatx4 accW[4][2];
    #pragma unroll
    for (int tr = 0; tr < 4; ++tr) {
        accW[tr][0] = (floatx4){b2c0, b2c0, b2c0, b2c0};
        accW[tr][1] = (floatx4){b2c1, b2c1, b2c1, b2c1};
    }
    const half8* w2fp = (const half8*)w2f;
    #pragma unroll
    for (int kb = 0; kb < 4; ++kb) {
        half8 bf0 = w2fp[((l * 4 + kb) * 8 + fq * 2 + 0) * 64 + lane];
        half8 bf1 = w2fp[((l * 4 + kb) * 8 + fq * 2 + 1) * 64 + lane];
        #pragma unroll
        for (int tr = 0; tr < 4; ++tr) {
            half8 af = *(const half8*)&smem[(tr * 16 + l15) * TPITCH + kb * 32 + quad * 8];
            accW[tr][0] = __builtin_amdgcn_mfma_f32_16x16x32_f16(af, bf0, accW[tr][0], 0, 0, 0);
            accW[tr][1] = __builtin_amdgcn_mfma_f32_16x16x32_f16(af, bf1, accW[tr][1], 0, 0, 0);
        }
    }

    // ---- epilogue: msg = xh_z[zsrc] * Wm * Ce; M-reduce + cross-quad butterfly ----
    float s0 = 0.0f, s1 = 0.0f;
    #pragma unroll
    for (int tr = 0; tr < 4; ++tr) {
        #pragma unroll
        for (int r = 0; r < 4; ++r) {
            const int e = tr * 16 + quad * 4 + r;
            const float cee = ce_l[e];
            const float* xr = xh_z + (l * NZ + zs_l[e]) * FD + colbase;
            s0 += accW[tr][0][r] * cee * xr[0];
            s1 += accW[tr][1][r] * cee * xr[16];
        }
    }
    s0 += __shfl_xor(s0, 16); s0 += __shfl_xor(s0, 32);
    s1 += __shfl_xor(s1, 16); s1 += __shfl_xor(s1, 32);
    float* cacc = comp_acc + (l * NC + cid) * FD + fq * 32;
    if (quad == 0) {
        atomicAdd(&cacc[l15],      s0);
        atomicAdd(&cacc[l15 + 16], s1);
    }
}

// ---------- per-component update: accumulate into types_acc ----------
__global__ __launch_bounds__(128) void comp_kernel(
    const float* __restrict__ comp_acc, const float* __restrict__ countsf,
    const float* __restrict__ cf2w, const float* __restrict__ cf2b,
    const float* __restrict__ intw, const float* __restrict__ intb,
    float* __restrict__ types_acc)
{
    int c = blockIdx.x, l = blockIdx.y, f = threadIdx.x;
    __shared__ float comp[FD];
    __shared__ float sx[FD];
    comp[f] = comp_acc[(l * NC + c) * FD + f] / countsf[c];
    __syncthreads();
    float acc = cf2b[l * HD + f];
    const float* w = cf2w + l * FD * HD;
    #pragma unroll 8
    for (int k = 0; k < FD; ++k) acc = fmaf(comp[k], w[k * HD + f], acc);
    sx[f] = ssp(acc);
    __syncthreads();
    float acc2 = intb[l * HD + f];
    const float* wi = intw + l * HD * HD;
    #pragma unroll 8
    for (int k = 0; k < HD; ++k) acc2 = fmaf(sx[k], wi[k * HD + f], acc2);
    atomicAdd(&types_acc[c * HD + f], acc2);
}

// ---------- readout: types = emb[comps_z] + types_acc, folded in ----------
__global__ __launch_bounds__(64) void readout_kernel(
    const float* __restrict__ types_acc, const float* __restrict__ emb,
    const int* __restrict__ comps_z,
    const float* __restrict__ w1, const float* __restrict__ b1,
    const float* __restrict__ w2, const float* __restrict__ b2,
    float* __restrict__ out)
{
    int b = blockIdx.x, lane = threadIdx.x;
    float sum = 0.0f;
    for (int cc = 0; cc < NELEM; ++cc) {
        int c = b * NELEM + cc;
        int zc = comps_z[c];
        float acc = b1[lane];
        const float* ta = types_acc + c * HD;
        const float* eb = emb + zc * HD;
        #pragma unroll 8
        for (int k = 0; k < HD; ++k) acc = fmaf(ta[k] + eb[k], w1[k * 64 + lane], acc);
        sum += ssp(acc) * w2[lane];
    }
    #pragma unroll
    for (int s = 32; s > 0; s >>= 1) sum += __shfl_xor(sum, s);
    if (lane == 0) out[b] = sum + (float)NELEM * b2[0];
}

extern "C" void kernel_launch(void* const* d_in, const int* in_sizes, int n_in,
                              void* d_out, int out_size, void* d_ws, size_t ws_size,
                              hipStream_t stream) {
    (void)in_sizes; (void)n_in; (void)out_size; (void)ws_size;
    const float* pos     = (const float*)d_in[0];
    const float* emb     = (const float*)d_in[1];
    const float* mlp_w1  = (const float*)d_in[2];
    const float* mlp_b1  = (const float*)d_in[3];
    const float* mlp_w2  = (const float*)d_in[4];
    const float* mlp_b2  = (const float*)d_in[5];
    const float* cf1     = (const float*)d_in[6];
    const float* cf2w    = (const float*)d_in[7];
    const float* cf2b    = (const float*)d_in[8];
    const float* intw    = (const float*)d_in[9];
    const float* intb    = (const float*)d_in[10];
    const float* ow1     = (const float*)d_in[11];
    const float* ob1     = (const float*)d_in[12];
    const float* ow2     = (const float*)d_in[13];
    const float* ob2     = (const float*)d_in[14];
    const int*   z       = (const int*)d_in[15];
    const int*   comp_id = (const int*)d_in[16];
    const int*   ei      = (const int*)d_in[17];
    const int*   comps_z = (const int*)d_in[18];
    float* out = (float*)d_out;

    char* ws = (char*)d_ws;
    size_t off = 0;
    auto alloc = [&](size_t bytes) -> void* {
        void* p = ws + off;
        off += (bytes + 255) & ~(size_t)255;
        return p;
    };
    // zeroed prefix: comp_acc | hist | counts | types_acc
    float* comp_acc  = (float*)alloc((size_t)LL * NC * FD * 4);
    int*   hist      = (int*)  alloc(NC * 4);
    int*   counts    = (int*)  alloc(NC * 4);
    float* types_acc = (float*)alloc((size_t)NC * HD * 4);
    size_t zero_bytes = off;
    int*   astart   = (int*)  alloc(NC * 4);
    int*   cursor   = (int*)  alloc(NC * 4);
    float* countsf  = (float*)alloc(NC * 4);
    float* ew_s     = (float*)alloc((size_t)PADE * 4);
    float* c_s      = (float*)alloc((size_t)PADE * 4);
    int*   zsrc_s   = (int*)  alloc((size_t)PADE * 4);
    int*   cid_s    = (int*)  alloc((size_t)PADE * 4);
    float* xh_z     = (float*)alloc((size_t)LL * NZ * FD * 4);
    _Float16* w1f   = (_Float16*)alloc((size_t)W1F_ELEMS * 2);
    _Float16* w2f   = (_Float16*)alloc((size_t)W2F_ELEMS * 2);

    hipMemsetAsync(d_ws, 0, zero_bytes, stream);

    prep_counts  <<<NEDGE / 256, 256, 0, stream>>>(ei, comp_id, hist, counts);
    scan_offsets <<<1, 256, 0, stream>>>(hist, counts, astart, cursor, countsf);
    fill_dummy   <<<NC, 256, 0, stream>>>(astart, hist, ew_s, c_s, zsrc_s, cid_s);
    scatter_edges<<<NEDGE / 256, 256, 0, stream>>>(pos, ei, comp_id, z, cursor,
                                                   ew_s, c_s, zsrc_s, cid_s);
    make_frags   <<<(W1F_ELEMS + W2F_ELEMS) / 256, 256, 0, stream>>>(mlp_w1, mlp_w2, w1f, w2f);
    xhz_kernel   <<<dim3(NZ / 2, LL), 256, 0, stream>>>(emb, cf1, xh_z);
    edge_kernel  <<<dim3(PADG, LL), 256, 0, stream>>>(ew_s, c_s, zsrc_s, cid_s,
                                                      w1f, mlp_b1, w2f, mlp_b2,
                                                      xh_z, comp_acc);
    comp_kernel  <<<dim3(NC, LL), 128, 0, stream>>>(comp_acc, countsf, cf2w, cf2b,
                                                    intw, intb, types_acc);
    readout_kernel<<<NGRAPH, 64, 0, stream>>>(types_acc, emb, comps_z,
                                              ow1, ob1, ow2, ob2, out);
}